// Round 1
// baseline (6313.003 us; speedup 1.0000x reference)
//
#include <hip/hip_runtime.h>
#include <hip/hip_bf16.h>

#define NEGF (-1000000000.0f)

namespace {

constexpr int B  = 64;
constexpr int N  = 50;
constexpr int NT = 30;
constexpr int T  = 60;
constexpr int S  = 90;          // NT + T
constexpr int NP1 = N + 1;      // 51
constexpr int NSMAX = N - 1;    // 49 spans max (width 2)
constexpr int SS = S * S;       // 8100
constexpr int KSPLIT = 9;
constexpr int KCH = SS / KSPLIT; // 900
constexpr int KT = 180;          // LDS K-tile
constexpr int CELLS = NT * NSMAX; // 1470
constexpr int ELSTRIDE = 92;     // padded row stride for el/er (bank-friendly)
constexpr int LSTR = 181;        // padded row stride for Et/Ot (odd -> conflict-free)
constexpr int ETROWS = 32;       // 30 valid + 2 pad rows (read-overrun safe)
constexpr int OTROWS = 56;       // 49 valid + pad rows (read-overrun safe)

__device__ __forceinline__ float bf_lo(unsigned int v){ return __uint_as_float(v << 16); }
__device__ __forceinline__ float bf_hi(unsigned int v){ return __uint_as_float(v & 0xFFFF0000u); }

__global__ void fill_neg(float* __restrict__ p, int count){
  int i = blockIdx.x * blockDim.x + threadIdx.x;
  if (i < count) p[i] = NEGF;
}

// width-1 spans: terminal states get unary scores; also per-span state-max mb.
__global__ void unary_init(const float* __restrict__ unary, float* __restrict__ beta,
                           float* __restrict__ mb){
  int k = blockIdx.x, b = blockIdx.y, j = threadIdx.x;
  float v = NEGF;
  if (j < T){
    v = unary[(b*N + k)*T + j];
    beta[((b*NP1 + k)*NP1 + (k+1))*S + NT + j] = v;
  }
  #pragma unroll
  for (int off = 32; off > 0; off >>= 1) v = fmaxf(v, __shfl_down(v, off));
  if (j == 0) mb[(b*NP1 + k)*NP1 + (k+1)] = v;
}

// m_rule[b,p] = max_{l,r} rule; erule = bf16(exp(rule - m_rule))
__global__ __launch_bounds__(256) void rule_prep(const float* __restrict__ rule,
                                                 float* __restrict__ m_rule,
                                                 __hip_bfloat16* __restrict__ erule){
  int p = blockIdx.x, b = blockIdx.y, tid = threadIdx.x;
  int base = (b*NT + p) * SS;
  float lm = NEGF;
  for (int i = tid; i < SS; i += 256) lm = fmaxf(lm, rule[base + i]);
  #pragma unroll
  for (int off = 32; off > 0; off >>= 1) lm = fmaxf(lm, __shfl_xor(lm, off));
  __shared__ float wmax[4];
  __shared__ float sm;
  if ((tid & 63) == 0) wmax[tid >> 6] = lm;
  __syncthreads();
  if (tid == 0){
    float m = fmaxf(fmaxf(wmax[0], wmax[1]), fmaxf(wmax[2], wmax[3]));
    m_rule[b*NT + p] = m;
    sm = m;
  }
  __syncthreads();
  float m = sm;
  for (int i = tid; i < SS; i += 256)
    erule[base + i] = __float2bfloat16(__expf(rule[base + i] - m));
}

// Per span (b,s) of width w: O[l,r] = sum_k exp(L_k[l]+R_k[r]-M), written bf16.
// Also M -> Mbuf. Thread tile: 15x15 active threads, 6x6 cells each.
__global__ __launch_bounds__(256) void stage1(int w, const float* __restrict__ beta,
                                              const float* __restrict__ mb,
                                              float* __restrict__ Mbuf,
                                              __hip_bfloat16* __restrict__ Og){
  int s = blockIdx.x, b = blockIdx.y, e = s + w, tid = threadIdx.x;
  int K = w - 1;
  __shared__ float smr[NSMAX];
  __shared__ float stmp[NSMAX];
  __shared__ float sM;
  __shared__ float el[NSMAX * ELSTRIDE];
  __shared__ float er[NSMAX * ELSTRIDE];

  if (tid < K){
    int u = s + tid + 1;
    float ml = mb[(b*NP1 + s)*NP1 + u];
    float mr = mb[(b*NP1 + u)*NP1 + e];
    smr[tid] = mr;
    stmp[tid] = ml + mr;
  }
  __syncthreads();
  if (tid == 0){
    float M = NEGF;
    for (int k = 0; k < K; ++k) M = fmaxf(M, stmp[k]);
    sM = M;
    Mbuf[b*NSMAX + s] = M;
  }
  __syncthreads();
  float M = sM;

  for (int idx = tid; idx < K * S; idx += 256){
    int k = idx / S;
    int i = idx - k * S;
    int u = s + k + 1;
    float mr = smr[k];
    el[k*ELSTRIDE + i] = __expf(beta[((b*NP1 + s)*NP1 + u)*S + i] + mr - M);
    er[k*ELSTRIDE + i] = __expf(beta[((b*NP1 + u)*NP1 + e)*S + i] - mr);
  }
  __syncthreads();

  int tr = tid >> 4, tc = tid & 15;
  if (tr >= 15 || tc >= 15) return;  // 15*6 = 90 exactly; no syncs after this point
  int l0 = tr * 6, r0 = tc * 6;
  float acc[6][6];
  #pragma unroll
  for (int i = 0; i < 6; ++i)
    #pragma unroll
    for (int j = 0; j < 6; ++j) acc[i][j] = 0.f;

  for (int k = 0; k < K; ++k){
    float la[6], ra[6];
    #pragma unroll
    for (int i = 0; i < 6; ++i){ la[i] = el[k*ELSTRIDE + l0 + i]; ra[i] = er[k*ELSTRIDE + r0 + i]; }
    #pragma unroll
    for (int i = 0; i < 6; ++i)
      #pragma unroll
      for (int j = 0; j < 6; ++j) acc[i][j] += la[i] * ra[j];
  }

  int obase = (b*NSMAX + s) * SS;
  #pragma unroll
  for (int i = 0; i < 6; ++i)
    #pragma unroll
    for (int j = 0; j < 6; ++j)
      Og[obase + (l0 + i)*S + (r0 + j)] = __float2bfloat16(acc[i][j]);
}

// Per (kchunk, b): partial C[p,s] = sum_{kk in chunk} erule[p,kk] * O[s,kk].
// 4 k-groups of 64 lanes; per-lane 4p x 7s register tile; LDS strides odd -> conflict-free.
__global__ __launch_bounds__(256) void stage2(int ns, const __hip_bfloat16* __restrict__ erule,
                                              const __hip_bfloat16* __restrict__ Og,
                                              float* __restrict__ Cpart){
  int kc = blockIdx.x, b = blockIdx.y, tid = threadIdx.x;
  __shared__ float smem[ETROWS*LSTR + OTROWS*LSTR];  // 63,712 bytes (< 64 KiB)
  float* Et = smem;
  float* Ot = smem + ETROWS*LSTR;

  int g = tid >> 6, lane = tid & 63, lp = lane >> 3, lsx = lane & 7;
  int p0 = lp * 4, s0 = lsx * 7;
  float acc[4][7];
  #pragma unroll
  for (int i = 0; i < 4; ++i)
    #pragma unroll
    for (int j = 0; j < 7; ++j) acc[i][j] = 0.f;

  int k0 = kc * KCH;
  for (int tt = 0; tt < KCH / KT; ++tt){
    int kb = k0 + tt * KT;
    for (int idx = tid; idx < NT * (KT/2); idx += 256){
      int p = idx / (KT/2), kk2 = idx - p * (KT/2);
      unsigned int v = *(const unsigned int*)(erule + (b*NT + p)*SS + kb + 2*kk2);
      Et[p*LSTR + 2*kk2]     = bf_lo(v);
      Et[p*LSTR + 2*kk2 + 1] = bf_hi(v);
    }
    for (int idx = tid; idx < ns * (KT/2); idx += 256){
      int si = idx / (KT/2), kk2 = idx - si * (KT/2);
      unsigned int v = *(const unsigned int*)(Og + (b*NSMAX + si)*SS + kb + 2*kk2);
      Ot[si*LSTR + 2*kk2]     = bf_lo(v);
      Ot[si*LSTR + 2*kk2 + 1] = bf_hi(v);
    }
    __syncthreads();
    int kbeg = g * (KT/4);
    for (int kk = kbeg; kk < kbeg + KT/4; ++kk){
      float la[4], lb[7];
      #pragma unroll
      for (int i = 0; i < 4; ++i) la[i] = Et[(p0 + i)*LSTR + kk];
      #pragma unroll
      for (int j = 0; j < 7; ++j) lb[j] = Ot[(s0 + j)*LSTR + kk];
      #pragma unroll
      for (int i = 0; i < 4; ++i)
        #pragma unroll
        for (int j = 0; j < 7; ++j) acc[i][j] += la[i] * lb[j];
    }
    __syncthreads();
  }

  // cross-k-group reduction through LDS overlay (no atomics -> deterministic)
  float* Cblk = smem;
  #pragma unroll
  for (int i = 0; i < 4; ++i)
    #pragma unroll
    for (int j = 0; j < 7; ++j){
      int p = p0 + i, si = s0 + j;
      if (p < NT && si < ns) Cblk[g*CELLS + p*ns + si] = acc[i][j];
    }
  __syncthreads();
  for (int cell = tid; cell < NT * ns; cell += 256){
    float v = Cblk[cell] + Cblk[CELLS + cell] + Cblk[2*CELLS + cell] + Cblk[3*CELLS + cell];
    Cpart[(kc*B + b)*CELLS + cell] = v;
  }
}

// beta[b,s,s+w,p] = log(sum_kc Cpart) + M[b,s] + m_rule[b,p]; mb = max_p.
__global__ __launch_bounds__(256) void finalize(int w, int ns, const float* __restrict__ Cpart,
                                                const float* __restrict__ Mbuf,
                                                const float* __restrict__ m_rule,
                                                float* __restrict__ beta, float* __restrict__ mb){
  int b = blockIdx.x, tid = threadIdx.x;
  __shared__ float vals[CELLS];
  for (int cell = tid; cell < NT * ns; cell += 256){
    int p = cell / ns, si = cell - p * ns;
    float sum = 0.f;
    #pragma unroll
    for (int kc = 0; kc < KSPLIT; ++kc) sum += Cpart[(kc*B + b)*CELLS + cell];
    float v = __logf(fmaxf(sum, 1e-37f)) + Mbuf[b*NSMAX + si] + m_rule[b*NT + p];
    beta[((b*NP1 + si)*NP1 + (si + w))*S + p] = v;
    vals[si*NT + p] = v;
  }
  __syncthreads();
  if (tid < ns){
    float m = NEGF;
    for (int p = 0; p < NT; ++p) m = fmaxf(m, vals[tid*NT + p]);
    mb[(b*NP1 + tid)*NP1 + (tid + w)] = m;
  }
}

__global__ void root_lse(const float* __restrict__ beta, const float* __restrict__ root,
                         float* __restrict__ out){
  int b = blockIdx.x, j = threadIdx.x;
  float v = (j < NT) ? beta[((b*NP1 + 0)*NP1 + N)*S + j] + root[b*NT + j] : NEGF;
  float m = v;
  #pragma unroll
  for (int off = 32; off > 0; off >>= 1) m = fmaxf(m, __shfl_xor(m, off));
  float ex = __expf(v - m);
  #pragma unroll
  for (int off = 32; off > 0; off >>= 1) ex += __shfl_xor(ex, off);
  if (j == 0) out[b] = __logf(ex) + m;
}

} // namespace

extern "C" void kernel_launch(void* const* d_in, const int* in_sizes, int n_in,
                              void* d_out, int out_size, void* d_ws, size_t ws_size,
                              hipStream_t stream){
  (void)in_sizes; (void)n_in; (void)out_size; (void)ws_size;
  const float* unary = (const float*)d_in[0];
  const float* rule  = (const float*)d_in[1];
  const float* root  = (const float*)d_in[2];

  char* ws = (char*)d_ws;
  size_t off = 0;
  auto alloc = [&](size_t bytes) -> void* {
    void* p = ws + off;
    off += (bytes + 255) & ~(size_t)255;
    return p;
  };
  // total ~146 MB of workspace
  float* beta   = (float*)alloc(sizeof(float) * (size_t)B * NP1 * NP1 * S);   // 59.9 MB
  float* mb     = (float*)alloc(sizeof(float) * (size_t)B * NP1 * NP1);       // 0.67 MB
  float* m_rule = (float*)alloc(sizeof(float) * B * NT);
  float* Mbuf   = (float*)alloc(sizeof(float) * B * NSMAX);
  float* Cpart  = (float*)alloc(sizeof(float) * KSPLIT * B * CELLS);          // 3.4 MB
  __hip_bfloat16* erule = (__hip_bfloat16*)alloc(sizeof(__hip_bfloat16) * (size_t)B * NT * SS);    // 31.1 MB
  __hip_bfloat16* Og    = (__hip_bfloat16*)alloc(sizeof(__hip_bfloat16) * (size_t)B * NSMAX * SS); // 50.8 MB

  int betaCount = B * NP1 * NP1 * S;
  fill_neg<<<dim3((betaCount + 255) / 256), dim3(256), 0, stream>>>(beta, betaCount);
  int mbCount = B * NP1 * NP1;
  fill_neg<<<dim3((mbCount + 255) / 256), dim3(256), 0, stream>>>(mb, mbCount);
  unary_init<<<dim3(N, B), dim3(64), 0, stream>>>(unary, beta, mb);
  rule_prep<<<dim3(NT, B), dim3(256), 0, stream>>>(rule, m_rule, erule);

  for (int w = 2; w <= N; ++w){
    int ns = N - w + 1;
    stage1<<<dim3(ns, B), dim3(256), 0, stream>>>(w, beta, mb, Mbuf, Og);
    stage2<<<dim3(KSPLIT, B), dim3(256), 0, stream>>>(ns, erule, Og, Cpart);
    finalize<<<dim3(B), dim3(256), 0, stream>>>(w, ns, Cpart, Mbuf, m_rule, beta, mb);
  }
  root_lse<<<dim3(B), dim3(64), 0, stream>>>(beta, root, (float*)d_out);
}